// Round 4
// baseline (339.491 us; speedup 1.0000x reference)
//
#include <hip/hip_runtime.h>
#include <hip/hip_bf16.h>

#define N_NODES 50000
#define DIM 256
#define N_EDGES 1600000
#define NBUK 196            // buckets of 256 nodes: 196*256 = 50176 >= 50000
#define CHUNK_E 4096        // edges per binning block
#define NBLK ((N_EDGES + CHUNK_E - 1) / CHUNK_E)   // 391
#define NCHUNK 8            // Y column chunks (32 cols each), one per XCD
#define AGG_BPC 320         // aggregate blocks per chunk

typedef float f32x4 __attribute__((ext_vector_type(4)));
typedef __bf16 bf16x8 __attribute__((ext_vector_type(8)));
typedef __bf16 bf16x4 __attribute__((ext_vector_type(4)));

// ---------------- W -> bf16 ----------------
__global__ void convw_k(const float* __restrict__ W, __bf16* __restrict__ Wbf) {
    int i = blockIdx.x * blockDim.x + threadIdx.x;
    if (i < DIM * DIM) Wbf[i] = (__bf16)W[i];
}

// ---------------- Y = feature @ W.T  (bf16 MFMA, no LDS) ----------------
// Output layout: Yc[chunk][node][32] with chunk = col>>5  (chunk-major, 3.2MB/chunk)
__global__ __launch_bounds__(256) void gemm_y(const float* __restrict__ feat,
                                              const __bf16* __restrict__ Wbf,
                                              __bf16* __restrict__ Yc) {
    const int wid  = threadIdx.x >> 6;
    const int lane = threadIdx.x & 63;
    const int row0 = blockIdx.x * 64 + wid * 16;
    const int mrow = lane & 15;
    const int kgrp = lane >> 4;          // 0..3

    int arow = row0 + mrow;
    int arow_c = arow < N_NODES ? arow : (N_NODES - 1);
    const float* aptr = feat + (size_t)arow_c * DIM + kgrp * 8;

    f32x4 acc[16];
#pragma unroll
    for (int i = 0; i < 16; ++i) acc[i] = (f32x4)0.0f;

#pragma unroll
    for (int ks = 0; ks < 8; ++ks) {
        const float* ap = aptr + ks * 32;
        f32x4 a0 = *(const f32x4*)(ap);
        f32x4 a1 = *(const f32x4*)(ap + 4);
        bf16x8 af;
        af[0] = (__bf16)a0[0]; af[1] = (__bf16)a0[1];
        af[2] = (__bf16)a0[2]; af[3] = (__bf16)a0[3];
        af[4] = (__bf16)a1[0]; af[5] = (__bf16)a1[1];
        af[6] = (__bf16)a1[2]; af[7] = (__bf16)a1[3];
#pragma unroll
        for (int nt = 0; nt < 16; ++nt) {
            int ncol = nt * 16 + mrow;   // B col for this lane
            const bf16x8 bf = *(const bf16x8*)(Wbf + (size_t)ncol * DIM + ks * 32 + kgrp * 8);
            acc[nt] = __builtin_amdgcn_mfma_f32_16x16x32_bf16(af, bf, acc[nt], 0, 0, 0);
        }
    }

    // C/D layout (m89): col = lane&15 (mrow), row = (lane>>4)*4 + reg
    int crow_base = row0 + kgrp * 4;
#pragma unroll
    for (int r = 0; r < 4; ++r) {
        int crow = crow_base + r;
        if (crow < N_NODES) {
#pragma unroll
            for (int nt = 0; nt < 16; ++nt) {
                // col = nt*16 + mrow -> chunk = nt>>1, within-chunk col = (nt&1)*16 + mrow
                __bf16* yp = Yc + (size_t)(nt >> 1) * N_NODES * 32
                               + (size_t)crow * 32 + (nt & 1) * 16 + mrow;
                *yp = (__bf16)acc[nt][r];
            }
        }
    }
}

// ---------------- bucket counts: per-block LDS hist, then aggregated atomics ----
__global__ __launch_bounds__(256) void count_k(const int* __restrict__ dst,
                                               int* __restrict__ gbkt) {
    __shared__ int lh[NBUK];
    for (int i = threadIdx.x; i < NBUK; i += 256) lh[i] = 0;
    __syncthreads();
    int base = blockIdx.x * CHUNK_E;
    int end = base + CHUNK_E; if (end > N_EDGES) end = N_EDGES;
    for (int e = base + threadIdx.x; e < end; e += 256)
        atomicAdd(&lh[dst[e] >> 8], 1);
    __syncthreads();
    for (int i = threadIdx.x; i < NBUK; i += 256)
        if (lh[i]) atomicAdd(&gbkt[i], lh[i]);
}

// ---------------- exclusive scan of 196 bucket totals ----------------
__global__ __launch_bounds__(256) void scanB_k(const int* __restrict__ gbkt,
                                               int* __restrict__ bbase,
                                               int* __restrict__ bcur,
                                               int* __restrict__ offsets) {
    __shared__ int sm[256];
    int t = threadIdx.x;
    int v = (t < NBUK) ? gbkt[t] : 0;
    sm[t] = v;
    __syncthreads();
    for (int off = 1; off < 256; off <<= 1) {
        int x = (t >= off) ? sm[t - off] : 0;
        __syncthreads();
        sm[t] += x;
        __syncthreads();
    }
    int excl = sm[t] - v;
    if (t < NBUK) { bbase[t] = excl; bcur[t] = excl; }
    if (t == 0) offsets[N_NODES] = N_EDGES;
}

// ---------------- place edges into bucket regions (block-local binning) --------
__global__ __launch_bounds__(256) void place_k(const int* __restrict__ src,
                                               const int* __restrict__ dst,
                                               int* __restrict__ bcur,
                                               unsigned int* __restrict__ staged) {
    __shared__ int lh[NBUK];
    __shared__ int lbase[NBUK];
    for (int i = threadIdx.x; i < NBUK; i += 256) lh[i] = 0;
    __syncthreads();
    int base = blockIdx.x * CHUNK_E;
    int end = base + CHUNK_E; if (end > N_EDGES) end = N_EDGES;
    for (int e = base + threadIdx.x; e < end; e += 256)
        atomicAdd(&lh[dst[e] >> 8], 1);
    __syncthreads();
    for (int i = threadIdx.x; i < NBUK; i += 256) {
        int c = lh[i];
        lbase[i] = c ? atomicAdd(&bcur[i], c) : 0;
        lh[i] = 0;                 // reuse as local cursor
    }
    __syncthreads();
    for (int e = base + threadIdx.x; e < end; e += 256) {
        int d = dst[e];
        int s = src[e];            // < 50000 -> fits in 16 bits
        int b = d >> 8;
        int p = atomicAdd(&lh[b], 1);
        staged[lbase[b] + p] = (unsigned int)s | ((unsigned int)(d & 255) << 16);
    }
}

// ---------------- per-bucket finalize: node offsets + CSR edge_src ----------------
__global__ __launch_bounds__(256) void finalize_k(const unsigned int* __restrict__ staged,
                                                  const int* __restrict__ bbase,
                                                  const int* __restrict__ gbkt,
                                                  int* __restrict__ offsets,
                                                  int* __restrict__ edge_src) {
    __shared__ int nh[256];
    __shared__ int nbase[256];
    __shared__ int sm[256];
    int t = threadIdx.x, b = blockIdx.x;
    int beg = bbase[b];
    int cnt = gbkt[b];
    nh[t] = 0;
    __syncthreads();
    for (int i = t; i < cnt; i += 256)
        atomicAdd(&nh[staged[beg + i] >> 16], 1);
    __syncthreads();
    int v = nh[t];
    sm[t] = v;
    __syncthreads();
    for (int off = 1; off < 256; off <<= 1) {
        int x = (t >= off) ? sm[t - off] : 0;
        __syncthreads();
        sm[t] += x;
        __syncthreads();
    }
    nbase[t] = sm[t] - v;
    int node = (b << 8) + t;
    if (node < N_NODES) offsets[node] = beg + nbase[t];
    nh[t] = 0;                     // reuse as per-node cursor
    __syncthreads();
    for (int i = t; i < cnt; i += 256) {
        unsigned int u = staged[beg + i];
        int dl = (int)(u >> 16);
        int p = atomicAdd(&nh[dl], 1);
        edge_src[beg + nbase[dl] + p] = (int)(u & 0xFFFFu);
    }
}

// ---------------- per-node gather-mean + bias, column-chunked ----------------
// chunk = blockIdx % 8 (aligns with XCD); per-XCD working set = 3.2MB (L2-resident)
// wave = 1 node: 8 edges in flight x 8 lanes/edge (bf16x4 = 8B each, 64B/edge)
__global__ __launch_bounds__(256) void aggregate_k(const __bf16* __restrict__ Yc,
                                                   const int* __restrict__ offsets,
                                                   const int* __restrict__ edge_src,
                                                   const float* __restrict__ bias,
                                                   float* __restrict__ out) {
    const int chunk = blockIdx.x & 7;
    const int bic   = blockIdx.x >> 3;      // block index within chunk
    const int wid   = threadIdx.x >> 6;
    const int lane  = threadIdx.x & 63;
    const int seg   = lane >> 3;            // edge slot 0..7
    const int cl    = (lane & 7) * 4;       // col within chunk (0,4,...,28)

    const __bf16* Ybase = Yc + (size_t)chunk * N_NODES * 32;
    const f32x4 bv = *(const f32x4*)(bias + chunk * 32 + cl);

    for (int node = bic * 4 + wid; node < N_NODES; node += AGG_BPC * 4) {
        int beg = offsets[node];
        int end = offsets[node + 1];

        float a0 = 0.f, a1 = 0.f, a2 = 0.f, a3 = 0.f;
        for (int j = beg + seg; j < end; j += 8) {
            int s = edge_src[j];
            bf16x4 v = *(const bf16x4*)(Ybase + (size_t)s * 32 + cl);
            a0 += (float)v[0];
            a1 += (float)v[1];
            a2 += (float)v[2];
            a3 += (float)v[3];
        }
        // reduce across the 8 edge slots (stride-8 lanes hold same columns)
#pragma unroll
        for (int m = 8; m < 64; m <<= 1) {
            a0 += __shfl_xor(a0, m);
            a1 += __shfl_xor(a1, m);
            a2 += __shfl_xor(a2, m);
            a3 += __shfl_xor(a3, m);
        }

        int deg = end - beg;
        f32x4 r;
        if (deg > 0) {
            float inv = 1.0f / (float)deg;
            r[0] = a0 * inv + bv[0];
            r[1] = a1 * inv + bv[1];
            r[2] = a2 * inv + bv[2];
            r[3] = a3 * inv + bv[3];
        } else {
            bf16x4 v = *(const bf16x4*)(Ybase + (size_t)node * 32 + cl);
            r[0] = (float)v[0] + bv[0];
            r[1] = (float)v[1] + bv[1];
            r[2] = (float)v[2] + bv[2];
            r[3] = (float)v[3] + bv[3];
        }
        if (seg == 0)   // lanes 0..7 write 128B contiguous
            *(f32x4*)(out + (size_t)node * DIM + chunk * 32 + cl) = r;
    }
}

static inline size_t align64(size_t x) { return (x + 63) & ~(size_t)63; }

extern "C" void kernel_launch(void* const* d_in, const int* in_sizes, int n_in,
                              void* d_out, int out_size, void* d_ws, size_t ws_size,
                              hipStream_t stream) {
    const float* feature = (const float*)d_in[0];
    const int*   src     = (const int*)d_in[1];
    const int*   dst     = (const int*)d_in[2];
    const float* W       = (const float*)d_in[3];
    const float* b       = (const float*)d_in[4];
    float* out = (float*)d_out;

    // workspace layout (~38.8 MB total)
    char* ws = (char*)d_ws;
    __bf16* Yc  = (__bf16*)ws;               ws += align64((size_t)N_NODES * DIM * 2);
    __bf16* Wbf = (__bf16*)ws;               ws += align64((size_t)DIM * DIM * 2);
    int* offsets  = (int*)ws;                ws += align64((size_t)(N_NODES + 1) * 4);
    int* gbkt     = (int*)ws;                ws += align64((size_t)NBUK * 4);
    int* bbase    = (int*)ws;                ws += align64((size_t)NBUK * 4);
    int* bcur     = (int*)ws;                ws += align64((size_t)NBUK * 4);
    unsigned int* staged = (unsigned int*)ws; ws += align64((size_t)N_EDGES * 4);
    int* edge_src = (int*)ws;                ws += align64((size_t)N_EDGES * 4);

    hipMemsetAsync(gbkt, 0, (size_t)NBUK * 4, stream);

    convw_k<<<(DIM * DIM + 255) / 256, 256, 0, stream>>>(W, Wbf);
    gemm_y<<<(N_NODES + 63) / 64, 256, 0, stream>>>(feature, Wbf, Yc);
    count_k<<<NBLK, 256, 0, stream>>>(dst, gbkt);
    scanB_k<<<1, 256, 0, stream>>>(gbkt, bbase, bcur, offsets);
    place_k<<<NBLK, 256, 0, stream>>>(src, dst, bcur, staged);
    finalize_k<<<NBUK, 256, 0, stream>>>(staged, bbase, gbkt, offsets, edge_src);
    aggregate_k<<<NCHUNK * AGG_BPC, 256, 0, stream>>>(Yc, offsets, edge_src, b, out);
}

// Round 5
// 248.127 us; speedup vs baseline: 1.3682x; 1.3682x over previous
//
#include <hip/hip_runtime.h>
#include <hip/hip_bf16.h>

#define N_NODES 50000
#define DIM 256
#define N_EDGES 1600000
#define NBUK 196            // buckets of 256 nodes: 196*256 = 50176 >= 50000
#define CHUNK_E 4096        // edges per binning block
#define NBLK ((N_EDGES + CHUNK_E - 1) / CHUNK_E)   // 391
#define NCHUNK 8            // Y column chunks (32 cols each), one per XCD
#define AGG_BPC 320         // aggregate blocks per chunk
#define NGROUP (N_NODES / 8)   // 6250 groups of 8 nodes

typedef float f32x4 __attribute__((ext_vector_type(4)));
typedef __bf16 bf16x8 __attribute__((ext_vector_type(8)));
typedef __bf16 bf16x4 __attribute__((ext_vector_type(4)));

// ---------------- W -> bf16 ----------------
__global__ void convw_k(const float* __restrict__ W, __bf16* __restrict__ Wbf) {
    int i = blockIdx.x * blockDim.x + threadIdx.x;
    if (i < DIM * DIM) Wbf[i] = (__bf16)W[i];
}

// ---------------- Y = feature @ W.T  (bf16 MFMA, no LDS) ----------------
// Output layout: Yc[chunk][node][32] with chunk = col>>5  (chunk-major, 3.2MB/chunk)
__global__ __launch_bounds__(256) void gemm_y(const float* __restrict__ feat,
                                              const __bf16* __restrict__ Wbf,
                                              __bf16* __restrict__ Yc) {
    const int wid  = threadIdx.x >> 6;
    const int lane = threadIdx.x & 63;
    const int row0 = blockIdx.x * 64 + wid * 16;
    const int mrow = lane & 15;
    const int kgrp = lane >> 4;          // 0..3

    int arow = row0 + mrow;
    int arow_c = arow < N_NODES ? arow : (N_NODES - 1);
    const float* aptr = feat + (size_t)arow_c * DIM + kgrp * 8;

    f32x4 acc[16];
#pragma unroll
    for (int i = 0; i < 16; ++i) acc[i] = (f32x4)0.0f;

#pragma unroll
    for (int ks = 0; ks < 8; ++ks) {
        const float* ap = aptr + ks * 32;
        f32x4 a0 = *(const f32x4*)(ap);
        f32x4 a1 = *(const f32x4*)(ap + 4);
        bf16x8 af;
        af[0] = (__bf16)a0[0]; af[1] = (__bf16)a0[1];
        af[2] = (__bf16)a0[2]; af[3] = (__bf16)a0[3];
        af[4] = (__bf16)a1[0]; af[5] = (__bf16)a1[1];
        af[6] = (__bf16)a1[2]; af[7] = (__bf16)a1[3];
#pragma unroll
        for (int nt = 0; nt < 16; ++nt) {
            int ncol = nt * 16 + mrow;   // B col for this lane
            const bf16x8 bf = *(const bf16x8*)(Wbf + (size_t)ncol * DIM + ks * 32 + kgrp * 8);
            acc[nt] = __builtin_amdgcn_mfma_f32_16x16x32_bf16(af, bf, acc[nt], 0, 0, 0);
        }
    }

    // C/D layout (m89): col = lane&15 (mrow), row = (lane>>4)*4 + reg
    int crow_base = row0 + kgrp * 4;
#pragma unroll
    for (int r = 0; r < 4; ++r) {
        int crow = crow_base + r;
        if (crow < N_NODES) {
#pragma unroll
            for (int nt = 0; nt < 16; ++nt) {
                // col = nt*16 + mrow -> chunk = nt>>1, within-chunk col = (nt&1)*16 + mrow
                __bf16* yp = Yc + (size_t)(nt >> 1) * N_NODES * 32
                               + (size_t)crow * 32 + (nt & 1) * 16 + mrow;
                *yp = (__bf16)acc[nt][r];
            }
        }
    }
}

// ---------------- bucket counts: per-block LDS hist, then aggregated atomics ----
__global__ __launch_bounds__(256) void count_k(const int* __restrict__ dst,
                                               int* __restrict__ gbkt) {
    __shared__ int lh[NBUK];
    for (int i = threadIdx.x; i < NBUK; i += 256) lh[i] = 0;
    __syncthreads();
    int base = blockIdx.x * CHUNK_E;
    int end = base + CHUNK_E; if (end > N_EDGES) end = N_EDGES;
    for (int e = base + threadIdx.x; e < end; e += 256)
        atomicAdd(&lh[dst[e] >> 8], 1);
    __syncthreads();
    for (int i = threadIdx.x; i < NBUK; i += 256)
        if (lh[i]) atomicAdd(&gbkt[i], lh[i]);
}

// ---------------- exclusive scan of 196 bucket totals ----------------
__global__ __launch_bounds__(256) void scanB_k(const int* __restrict__ gbkt,
                                               int* __restrict__ bbase,
                                               int* __restrict__ bcur,
                                               int* __restrict__ offsets) {
    __shared__ int sm[256];
    int t = threadIdx.x;
    int v = (t < NBUK) ? gbkt[t] : 0;
    sm[t] = v;
    __syncthreads();
    for (int off = 1; off < 256; off <<= 1) {
        int x = (t >= off) ? sm[t - off] : 0;
        __syncthreads();
        sm[t] += x;
        __syncthreads();
    }
    int excl = sm[t] - v;
    if (t < NBUK) { bbase[t] = excl; bcur[t] = excl; }
    if (t == 0) offsets[N_NODES] = N_EDGES;
}

// ---------------- place edges into bucket regions (block-local binning) --------
__global__ __launch_bounds__(256) void place_k(const int* __restrict__ src,
                                               const int* __restrict__ dst,
                                               int* __restrict__ bcur,
                                               unsigned int* __restrict__ staged) {
    __shared__ int lh[NBUK];
    __shared__ int lbase[NBUK];
    for (int i = threadIdx.x; i < NBUK; i += 256) lh[i] = 0;
    __syncthreads();
    int base = blockIdx.x * CHUNK_E;
    int end = base + CHUNK_E; if (end > N_EDGES) end = N_EDGES;
    for (int e = base + threadIdx.x; e < end; e += 256)
        atomicAdd(&lh[dst[e] >> 8], 1);
    __syncthreads();
    for (int i = threadIdx.x; i < NBUK; i += 256) {
        int c = lh[i];
        lbase[i] = c ? atomicAdd(&bcur[i], c) : 0;
        lh[i] = 0;                 // reuse as local cursor
    }
    __syncthreads();
    for (int e = base + threadIdx.x; e < end; e += 256) {
        int d = dst[e];
        int s = src[e];            // < 50000 -> fits in 16 bits
        int b = d >> 8;
        int p = atomicAdd(&lh[b], 1);
        staged[lbase[b] + p] = (unsigned int)s | ((unsigned int)(d & 255) << 16);
    }
}

// ---------------- per-bucket finalize: node offsets + CSR edge_src ----------------
__global__ __launch_bounds__(256) void finalize_k(const unsigned int* __restrict__ staged,
                                                  const int* __restrict__ bbase,
                                                  const int* __restrict__ gbkt,
                                                  int* __restrict__ offsets,
                                                  int* __restrict__ edge_src) {
    __shared__ int nh[256];
    __shared__ int nbase[256];
    __shared__ int sm[256];
    int t = threadIdx.x, b = blockIdx.x;
    int beg = bbase[b];
    int cnt = gbkt[b];
    nh[t] = 0;
    __syncthreads();
    for (int i = t; i < cnt; i += 256)
        atomicAdd(&nh[staged[beg + i] >> 16], 1);
    __syncthreads();
    int v = nh[t];
    sm[t] = v;
    __syncthreads();
    for (int off = 1; off < 256; off <<= 1) {
        int x = (t >= off) ? sm[t - off] : 0;
        __syncthreads();
        sm[t] += x;
        __syncthreads();
    }
    nbase[t] = sm[t] - v;
    int node = (b << 8) + t;
    if (node < N_NODES) offsets[node] = beg + nbase[t];
    nh[t] = 0;                     // reuse as per-node cursor
    __syncthreads();
    for (int i = t; i < cnt; i += 256) {
        unsigned int u = staged[beg + i];
        int dl = (int)(u >> 16);
        int p = atomicAdd(&nh[dl], 1);
        edge_src[beg + nbase[dl] + p] = (int)(u & 0xFFFFu);
    }
}

// ---------------- per-node gather-mean + bias, column-chunked, no shuffles -----
// chunk = blockIdx & 7 (XCD round-robin); per-XCD working set = 3.2MB (L2-resident)
// wave = 8 nodes; segment (8 lanes) owns one node and iterates its edge list;
// lane covers 4 cols (bf16x4 = 8B); segment reads 64B/edge. Reduction is in-lane.
__global__ __launch_bounds__(256) void aggregate_k(const __bf16* __restrict__ Yc,
                                                   const int* __restrict__ offsets,
                                                   const int* __restrict__ edge_src,
                                                   const float* __restrict__ bias,
                                                   float* __restrict__ out) {
    const int chunk = blockIdx.x & 7;
    const int bic   = blockIdx.x >> 3;      // block index within chunk
    const int wid   = threadIdx.x >> 6;
    const int lane  = threadIdx.x & 63;
    const int seg   = lane >> 3;            // node slot 0..7
    const int cl    = (lane & 7) * 4;       // col within chunk (0,4,...,28)

    const __bf16* Ybase = Yc + (size_t)chunk * N_NODES * 32;
    const f32x4 bv = *(const f32x4*)(bias + chunk * 32 + cl);

    for (int g = bic * 4 + wid; g < NGROUP; g += AGG_BPC * 4) {
        const int node = g * 8 + seg;
        const int beg = offsets[node];
        const int end = offsets[node + 1];

        float a0 = 0.f, a1 = 0.f, a2 = 0.f, a3 = 0.f;
        int j = beg;
        for (; j + 3 < end; j += 4) {
            int s0 = edge_src[j];
            int s1 = edge_src[j + 1];
            int s2 = edge_src[j + 2];
            int s3 = edge_src[j + 3];
            bf16x4 v0 = *(const bf16x4*)(Ybase + (size_t)s0 * 32 + cl);
            bf16x4 v1 = *(const bf16x4*)(Ybase + (size_t)s1 * 32 + cl);
            bf16x4 v2 = *(const bf16x4*)(Ybase + (size_t)s2 * 32 + cl);
            bf16x4 v3 = *(const bf16x4*)(Ybase + (size_t)s3 * 32 + cl);
            a0 += (float)v0[0] + (float)v1[0] + (float)v2[0] + (float)v3[0];
            a1 += (float)v0[1] + (float)v1[1] + (float)v2[1] + (float)v3[1];
            a2 += (float)v0[2] + (float)v1[2] + (float)v2[2] + (float)v3[2];
            a3 += (float)v0[3] + (float)v1[3] + (float)v2[3] + (float)v3[3];
        }
        for (; j < end; ++j) {
            int s0 = edge_src[j];
            bf16x4 v0 = *(const bf16x4*)(Ybase + (size_t)s0 * 32 + cl);
            a0 += (float)v0[0];
            a1 += (float)v0[1];
            a2 += (float)v0[2];
            a3 += (float)v0[3];
        }

        const int deg = end - beg;
        f32x4 r;
        if (deg > 0) {
            float inv = 1.0f / (float)deg;
            r[0] = a0 * inv + bv[0];
            r[1] = a1 * inv + bv[1];
            r[2] = a2 * inv + bv[2];
            r[3] = a3 * inv + bv[3];
        } else {
            bf16x4 v = *(const bf16x4*)(Ybase + (size_t)node * 32 + cl);
            r[0] = (float)v[0] + bv[0];
            r[1] = (float)v[1] + bv[1];
            r[2] = (float)v[2] + bv[2];
            r[3] = (float)v[3] + bv[3];
        }
        // all 64 lanes write: 8 segments x 128B contiguous f32
        *(f32x4*)(out + (size_t)node * DIM + chunk * 32 + cl) = r;
    }
}

static inline size_t align64(size_t x) { return (x + 63) & ~(size_t)63; }

extern "C" void kernel_launch(void* const* d_in, const int* in_sizes, int n_in,
                              void* d_out, int out_size, void* d_ws, size_t ws_size,
                              hipStream_t stream) {
    const float* feature = (const float*)d_in[0];
    const int*   src     = (const int*)d_in[1];
    const int*   dst     = (const int*)d_in[2];
    const float* W       = (const float*)d_in[3];
    const float* b       = (const float*)d_in[4];
    float* out = (float*)d_out;

    // workspace layout (~38.8 MB total)
    char* ws = (char*)d_ws;
    __bf16* Yc  = (__bf16*)ws;               ws += align64((size_t)N_NODES * DIM * 2);
    __bf16* Wbf = (__bf16*)ws;               ws += align64((size_t)DIM * DIM * 2);
    int* offsets  = (int*)ws;                ws += align64((size_t)(N_NODES + 1) * 4);
    int* gbkt     = (int*)ws;                ws += align64((size_t)NBUK * 4);
    int* bbase    = (int*)ws;                ws += align64((size_t)NBUK * 4);
    int* bcur     = (int*)ws;                ws += align64((size_t)NBUK * 4);
    unsigned int* staged = (unsigned int*)ws; ws += align64((size_t)N_EDGES * 4);
    int* edge_src = (int*)ws;                ws += align64((size_t)N_EDGES * 4);

    hipMemsetAsync(gbkt, 0, (size_t)NBUK * 4, stream);

    convw_k<<<(DIM * DIM + 255) / 256, 256, 0, stream>>>(W, Wbf);
    gemm_y<<<(N_NODES + 63) / 64, 256, 0, stream>>>(feature, Wbf, Yc);
    count_k<<<NBLK, 256, 0, stream>>>(dst, gbkt);
    scanB_k<<<1, 256, 0, stream>>>(gbkt, bbase, bcur, offsets);
    place_k<<<NBLK, 256, 0, stream>>>(src, dst, bcur, staged);
    finalize_k<<<NBUK, 256, 0, stream>>>(staged, bbase, gbkt, offsets, edge_src);
    aggregate_k<<<NCHUNK * AGG_BPC, 256, 0, stream>>>(Yc, offsets, edge_src, b, out);
}